// Round 11
// baseline (185.222 us; speedup 1.0000x reference)
//
#include <hip/hip_runtime.h>
#include <math.h>

// Problem constants: N=2, T=1024, D=256, W=128, H=8, HD=32
#define NTOK 2048
#define TT   1024
constexpr float SCL = 0.17677669529663687f; // 1/sqrt(32)

// ---- workspace layout (in floats) ----
#define OFF_WQT 0
#define OFF_WKT 65536
#define OFF_WVT 131072
#define OFF_OWT 196608
#define OFF_RQ  262144          // 2048*2048 floats (rq, [i][s*16 + h*2 + par], scaled)
#define OFF_SB  4456448         // 2048*8 floats (score bias, scaled)
#define OFF_CTX 4472832         // 2048*2048 floats (ctx, [i][k*8+h])

// async global->LDS, 16B per lane; lds dst is wave-uniform base (HW adds lane*16)
#define GLOAD_LDS16(g, l)                                                      \
    __builtin_amdgcn_global_load_lds(                                          \
        (const __attribute__((address_space(1))) unsigned int*)(g),            \
        (__attribute__((address_space(3))) unsigned int*)(l), 16, 0, 0)

// ---------------- K0: transpose Wq,Wk,Wv,out_w into ws ----------------
__global__ __launch_bounds__(256) void k0_transpose(const float* __restrict__ ipw,
                                                    const float* __restrict__ ow,
                                                    float* __restrict__ ws) {
    __shared__ float tile[32][33];
    int bx = blockIdx.x;
    int mat = bx >> 6, tl = bx & 63;
    int tr0 = (tl >> 3) << 5, tc0 = (tl & 7) << 5;
    const float* src;
    float* dst;
    if (mat == 3) { src = ow;             dst = ws + OFF_OWT; }
    else          { src = ipw + mat*65536; dst = ws + OFF_WQT + mat*65536; }
    int c = threadIdx.x & 31, r0 = threadIdx.x >> 5;
    #pragma unroll
    for (int k = 0; k < 4; k++) {
        int r = r0 + k*8;
        tile[r][c] = src[(tr0 + r)*256 + tc0 + c];
    }
    __syncthreads();
    #pragma unroll
    for (int k = 0; k < 4; k++) {
        int r = r0 + k*8;
        dst[(tc0 + r)*256 + tr0 + c] = tile[c][r];
    }
}

// ---------------- K1: qh -> rq (Wk folded into q) + score bias ----------------
// rq stores staged in LDS, flushed as coalesced float4 (R8: 10x write-amp fix).
// dyn LDS = 67584 B: rqt[8][16*132] (plane layout [ii][h2p*132 + s])
__global__ __launch_bounds__(512) void k1_qrq(const float* __restrict__ x,
                                              const float* __restrict__ ipw,
                                              const float* __restrict__ ipb,
                                              float* __restrict__ ws) {
    __shared__ float x8[2048];     // 8 tokens x 256
    __shared__ float qpart[4096];  // 2 halves x 8 x 256
    __shared__ float qh[2048];     // 8 x 256
    extern __shared__ float rqt[]; // 8 x 2112 floats
    const float* wqT = ws + OFF_WQT;
    const float* wk  = ipw + 65536;   // Wk raw: wk[r*256 + c] = Wk[r][c]
    float* rqw = ws + OFF_RQ;
    float* sbw = ws + OFF_SB;
    int tid = threadIdx.x;
    long i0 = (long)blockIdx.x * 8;

    ((float4*)x8)[tid] = ((const float4*)(x + i0*256))[tid];
    __syncthreads();

    int c = tid & 255, half = tid >> 8;
    {   // qh partials over cc-half
        float qa[8];
        #pragma unroll
        for (int ii = 0; ii < 8; ii++) qa[ii] = 0.f;
        int cc0 = half*128;
        #pragma unroll 8
        for (int cc = cc0; cc < cc0 + 128; cc++) {
            float w = wqT[cc*256 + c];
            #pragma unroll
            for (int ii = 0; ii < 8; ii++) qa[ii] += x8[ii*256 + cc]*w;
        }
        #pragma unroll
        for (int ii = 0; ii < 8; ii++) qpart[(half*8 + ii)*256 + c] = qa[ii];
    }
    __syncthreads();
    if (tid < 256) {
        float b = ipb[tid];
        #pragma unroll
        for (int ii = 0; ii < 8; ii++)
            qh[ii*256 + tid] = qpart[ii*256 + tid] + qpart[(8 + ii)*256 + tid] + b;
    }
    __syncthreads();
    {   // rq compute -> LDS tile.  rq[h,k] = SCL * sum_hd qh[h*32+hd] * Wk[h*32+hd, k]
        int k = tid & 255, hh = tid >> 8;
        int s = k & 127, par = k >> 7;
        for (int h = hh*4; h < hh*4 + 4; h++) {
            float ra[8];
            #pragma unroll
            for (int ii = 0; ii < 8; ii++) ra[ii] = 0.f;
            #pragma unroll 8
            for (int hd = 0; hd < 32; hd++) {
                float w = wk[(h*32 + hd)*256 + k];   // coalesced over k
                #pragma unroll
                for (int ii = 0; ii < 8; ii++) ra[ii] += qh[ii*256 + h*32 + hd]*w;
            }
            // LDS plane layout: [ii][ (h*2+par)*132 + s ]  (lanes walk s: conflict-free)
            int h2p = h*2 + par;
            #pragma unroll
            for (int ii = 0; ii < 8; ii++)
                rqt[ii*2112 + h2p*132 + s] = ra[ii]*SCL;
        }
    }
    __syncthreads();
    {   // flush: global layout [i][s*16 + h2p], fully coalesced float4 stores
        float4* dst = (float4*)(rqw + i0*2048);
        #pragma unroll
        for (int it = 0; it < 8; it++) {
            int f = it*512 + tid;          // ii = it (512 float4 per token)
            int s = (f & 511) >> 2, q = f & 3;
            int base = it*2112 + s;
            float4 v;
            v.x = rqt[base + (4*q + 0)*132];
            v.y = rqt[base + (4*q + 1)*132];
            v.z = rqt[base + (4*q + 2)*132];
            v.w = rqt[base + (4*q + 3)*132];
            dst[f] = v;
        }
    }
    if (tid < 64) {  // score bias = (qh . bk_h)/sqrt(32)
        int ii = tid >> 3, h = tid & 7;
        float s = 0.f;
        #pragma unroll 8
        for (int hd = 0; hd < 32; hd++) s += qh[ii*256 + h*32 + hd]*ipb[256 + h*32 + hd];
        sbw[(i0 + ii)*8 + h] = s*SCL;
    }
}

// ---------------- K2: main attention (one block per token) ----------------
// dyn LDS = 157696 B: xw[128*260] | rq2[2048] (aliased by attn[1024]) | scp[4096]
// R10: xw row stride 260 (16B-aligned rows for b128 scores reads);
//      scores: wave=(q,hh) lane=j-pair, 3 DS/s (2 uniform b128 rq + 1 b128 xw)
__global__ __launch_bounds__(512) void k2_attn(const float* __restrict__ x,
                                               float* __restrict__ ws) {
    extern __shared__ float sm[];
    float* xw   = sm;                  // 33280 floats, row stride 260
    float* rq2  = sm + 33280;          // 2048 floats, [s*16 + h*2 + par]
    float* scp  = sm + 33280 + 2048;   // 4096 floats, [q*1024 + h*128 + j]
    float* attn = rq2;                 // alias (rq2 dead after scores)
    const float* rqw = ws + OFF_RQ;
    const float* sbw = ws + OFF_SB;
    float* ctxw = ws + OFF_CTX;
    int tid = threadIdx.x;
    int i = blockIdx.x;
    int t = i & (TT - 1);
    int w = tid >> 6, lane = tid & 63;

    // ---- stage window + rq via async global->LDS (1 row = 1 instruction) ----
    {
        #pragma unroll
        for (int it = 0; it < 16; it++) {
            int r = it*8 + w;                 // wave-uniform row
            int ts = t - 127 + r;
            float* lrow = xw + r*260;         // row is 1024B contiguous; pad untouched
            if (ts >= 0) {
                const float* g = x + (long)(i - 127 + r)*256 + lane*4;
                GLOAD_LDS16(g, lrow);
            } else {
                float4 z = {0.f, 0.f, 0.f, 0.f};
                *(float4*)(lrow + lane*4) = z;
            }
        }
        const float* g = rqw + (long)i*2048 + w*256 + lane*4;
        GLOAD_LDS16(g, rq2 + w*256);
    }
    __syncthreads();

    // ---- scores: wave (q=w>>1, hh=w&1); lane jj2 = j-pair; per s: 3 DS ----
    {
        int jj2 = lane;
        int q = w >> 1, hh = w & 1;
        float a00=0.f,a01=0.f,a10=0.f,a11=0.f,a20=0.f,a21=0.f,a30=0.f,a31=0.f;
        const float4* rq4 = (const float4*)rq2;
        int s0 = q*32;
        #pragma unroll 4
        for (int s = s0; s < s0 + 32; s++) {
            float4 xv = *(const float4*)&xw[s*260 + 4*jj2];   // (j0,p0)(j0,p1)(j1,p0)(j1,p1)
            float4 r0 = rq4[s*4 + hh*2];       // h=hb+0:(p0,p1), h=hb+1:(p0,p1)
            float4 r1 = rq4[s*4 + hh*2 + 1];   // h=hb+2, h=hb+3
            a00 += r0.x*xv.x + r0.y*xv.y;  a01 += r0.x*xv.z + r0.y*xv.w;
            a10 += r0.z*xv.x + r0.w*xv.y;  a11 += r0.z*xv.z + r0.w*xv.w;
            a20 += r1.x*xv.x + r1.y*xv.y;  a21 += r1.x*xv.z + r1.y*xv.w;
            a30 += r1.z*xv.x + r1.w*xv.y;  a31 += r1.z*xv.z + r1.w*xv.w;
        }
        int hb = hh*4;
        float2* sc2 = (float2*)scp;            // idx = q*512 + h*64 + jj2
        float2 v0 = {a00, a01}; sc2[q*512 + (hb+0)*64 + jj2] = v0;
        float2 v1 = {a10, a11}; sc2[q*512 + (hb+1)*64 + jj2] = v1;
        float2 v2 = {a20, a21}; sc2[q*512 + (hb+2)*64 + jj2] = v2;
        float2 v3 = {a30, a31}; sc2[q*512 + (hb+3)*64 + jj2] = v3;
    }
    __syncthreads();

    // ---- softmax: wave h (8 waves), lane l covers j=l and j=l+64 ----
    {
        int h = w, l = lane;
        float sb = sbw[i*8 + h];
        float s1 = sb, s2 = sb;
        #pragma unroll
        for (int q = 0; q < 4; q++) {
            s1 += scp[q*1024 + h*128 + l];
            s2 += scp[q*1024 + h*128 + l + 64];
        }
        int lim = 127 - t;
        bool m1 = l < lim, m2 = (l + 64) < lim;
        if (m1) s1 = -1e30f;
        if (m2) s2 = -1e30f;
        float m = fmaxf(s1, s2);
        #pragma unroll
        for (int d = 1; d < 64; d <<= 1) m = fmaxf(m, __shfl_xor(m, d, 64));
        float e1 = m1 ? 0.f : __expf(s1 - m);
        float e2 = m2 ? 0.f : __expf(s2 - m);
        float sum = e1 + e2;
        #pragma unroll
        for (int d = 1; d < 64; d <<= 1) sum += __shfl_xor(sum, d, 64);
        float r = 1.0f / sum;
        attn[l*8 + h] = e1*r;
        attn[(l + 64)*8 + h] = e2*r;
    }
    __syncthreads();

    // ---- ctx: thread (sC, jq) accumulates [p][h] (16 accs) over 32 j ----
    {
        int sC = tid & 127, jq = tid >> 7;
        float cac[16];
        #pragma unroll
        for (int c = 0; c < 16; c++) cac[c] = 0.f;
        #pragma unroll 4
        for (int j = jq*32; j < jq*32 + 32; j++) {
            float2 x2 = *(const float2*)&xw[sC*260 + 2*j];
            float4 a0 = *(const float4*)&attn[j*8];
            float4 a1 = *(const float4*)&attn[j*8 + 4];
            cac[0]  += a0.x*x2.x; cac[1]  += a0.y*x2.x; cac[2]  += a0.z*x2.x; cac[3]  += a0.w*x2.x;
            cac[4]  += a1.x*x2.x; cac[5]  += a1.y*x2.x; cac[6]  += a1.z*x2.x; cac[7]  += a1.w*x2.x;
            cac[8]  += a0.x*x2.y; cac[9]  += a0.y*x2.y; cac[10] += a0.z*x2.y; cac[11] += a0.w*x2.y;
            cac[12] += a1.x*x2.y; cac[13] += a1.y*x2.y; cac[14] += a1.z*x2.y; cac[15] += a1.w*x2.y;
        }
        __syncthreads();  // all xw reads done -> safe to overwrite xw with partials
        #pragma unroll
        for (int c = 0; c < 16; c++) xw[c*512 + tid] = cac[c];  // [c][thr], conflict-free
    }
    __syncthreads();

    // ---- reduce 4 j-quarters, write ctx[i][k*8+h] ----
    if (tid < 256) {
        int k = tid, p = k >> 7;
        float v[8];
        #pragma unroll
        for (int h = 0; h < 8; h++) v[h] = 0.f;
        #pragma unroll
        for (int jq = 0; jq < 4; jq++) {
            int thr = jq*128 + (k & 127);
            #pragma unroll
            for (int h = 0; h < 8; h++) v[h] += xw[(p*8 + h)*512 + thr];
        }
        float4* dst = (float4*)(ctxw + (long)i*2048 + k*8);
        float4 o0 = {v[0], v[1], v[2], v[3]};
        float4 o1 = {v[4], v[5], v[6], v[7]};
        dst[0] = o0; dst[1] = o1;
    }
}

// ---------------- K3: out = out_w @ (Wv_blockdiag @ ctx + bv) + out_b ----------------
// R10: ctx staged TRANSPOSED in LDS: ctx8T[kh8][ii] (padded quads) so the Wv
// loop reads 2 b128 per k instead of 8 strided b32.
// dyn LDS = 98304 B: ctx8T[18432] | oppart[4096] | op[2048]
__global__ __launch_bounds__(512) void k3_proj(const float* __restrict__ ipb,
                                               const float* __restrict__ ob,
                                               float* __restrict__ ws,
                                               float* __restrict__ out) {
    extern __shared__ float sm[];
    float* ctx8T  = sm;                    // idx(kh8,ii) = kh8*8 + (kh8>>2)*4 + ii
    float* oppart = sm + 18432;            // 2 x 8 x 256
    float* op     = sm + 18432 + 4096;     // 8 x 256
    const float* wvT  = ws + OFF_WVT;
    const float* owT  = ws + OFF_OWT;
    const float* ctxw = ws + OFF_CTX;
    int tid = threadIdx.x;
    long i0 = (long)blockIdx.x * 8;

    {   // stage transposed: global [ii][k*8+h] -> LDS [kh8][ii]
        const float4* src = (const float4*)(ctxw + i0*2048);
        #pragma unroll
        for (int it = 0; it < 8; it++) {
            float4 v = src[it*512 + tid];          // ii=it, kh8 = tid*4..+3
            int base = tid*4;
            #pragma unroll
            for (int m = 0; m < 4; m++) {
                int kh8 = base + m;
                ctx8T[kh8*8 + (kh8 >> 2)*4 + it] = (&v.x)[m];
            }
        }
    }
    __syncthreads();

    int c = tid & 255, kh = tid >> 8;
    {   // out_pre partials: per-head Wv fold (2 b128 ctx reads per k)
        int h = c >> 5;
        float acc[8];
        #pragma unroll
        for (int ii = 0; ii < 8; ii++) acc[ii] = 0.f;
        #pragma unroll 8
        for (int k = kh*128; k < kh*128 + 128; k++) {
            float w = wvT[k*256 + c];
            int kh8 = k*8 + h;
            int base = kh8*8 + (kh8 >> 2)*4;
            float4 c0 = *(const float4*)&ctx8T[base];
            float4 c1 = *(const float4*)&ctx8T[base + 4];
            acc[0] += w*c0.x; acc[1] += w*c0.y; acc[2] += w*c0.z; acc[3] += w*c0.w;
            acc[4] += w*c1.x; acc[5] += w*c1.y; acc[6] += w*c1.z; acc[7] += w*c1.w;
        }
        #pragma unroll
        for (int ii = 0; ii < 8; ii++) oppart[(kh*8 + ii)*256 + c] = acc[ii];
    }
    __syncthreads();
    if (tid < 256) {
        float b = ipb[512 + tid];
        #pragma unroll
        for (int ii = 0; ii < 8; ii++)
            op[ii*256 + tid] = oppart[ii*256 + tid] + oppart[(8 + ii)*256 + tid] + b;
    }
    __syncthreads();
    {   // final projection partials
        float acc[8];
        #pragma unroll
        for (int ii = 0; ii < 8; ii++) acc[ii] = 0.f;
        #pragma unroll 8
        for (int cc = kh*128; cc < kh*128 + 128; cc++) {
            float w = owT[cc*256 + c];
            #pragma unroll
            for (int ii = 0; ii < 8; ii++) acc[ii] += w*op[ii*256 + cc];
        }
        #pragma unroll
        for (int ii = 0; ii < 8; ii++) oppart[(kh*8 + ii)*256 + c] = acc[ii];
    }
    __syncthreads();
    if (tid < 256) {
        float b = ob[tid];
        #pragma unroll
        for (int ii = 0; ii < 8; ii++)
            out[(i0 + ii)*256 + tid] = oppart[ii*256 + tid] + oppart[(8 + ii)*256 + tid] + b;
    }
}

extern "C" void kernel_launch(void* const* d_in, const int* in_sizes, int n_in,
                              void* d_out, int out_size, void* d_ws, size_t ws_size,
                              hipStream_t stream) {
    const float* x   = (const float*)d_in[0];   // (2,1024,256)
    const float* ipw = (const float*)d_in[1];   // (768,256)
    const float* ipb = (const float*)d_in[2];   // (768)
    const float* ow  = (const float*)d_in[3];   // (256,256)
    const float* ob  = (const float*)d_in[4];   // (256)
    float* out = (float*)d_out;
    float* ws  = (float*)d_ws;                  // needs ~33.1 MB

    (void)in_sizes; (void)n_in; (void)out_size; (void)ws_size;

    // allow >64KB dynamic LDS (idempotent; host-side, graph-capture safe)
    hipFuncSetAttribute(reinterpret_cast<const void*>(k1_qrq),
                        hipFuncAttributeMaxDynamicSharedMemorySize, 67584);
    hipFuncSetAttribute(reinterpret_cast<const void*>(k2_attn),
                        hipFuncAttributeMaxDynamicSharedMemorySize, 157696);
    hipFuncSetAttribute(reinterpret_cast<const void*>(k3_proj),
                        hipFuncAttributeMaxDynamicSharedMemorySize, 98304);

    hipLaunchKernelGGL(k0_transpose, dim3(256),  dim3(256), 0,      stream, ipw, ow, ws);
    hipLaunchKernelGGL(k1_qrq,       dim3(256),  dim3(512), 67584,  stream, x, ipw, ipb, ws);
    hipLaunchKernelGGL(k2_attn,      dim3(2048), dim3(512), 157696, stream, x, ws);
    hipLaunchKernelGGL(k3_proj,      dim3(256),  dim3(512), 98304,  stream, ipb, ob, ws, out);
}

// Round 13
// 170.999 us; speedup vs baseline: 1.0832x; 1.0832x over previous
//
#include <hip/hip_runtime.h>
#include <math.h>

// Problem constants: N=2, T=1024, D=256, W=128, H=8, HD=32
#define NTOK 2048
#define TT   1024
constexpr float SCL = 0.17677669529663687f; // 1/sqrt(32)

// ---- workspace layout (in floats) ----
#define OFF_WQT 0
#define OFF_WKT 65536
#define OFF_WVT 131072
#define OFF_OWT 196608
#define OFF_RQ  262144          // 2048*2048 floats (rq, [i][s*16 + h*2 + par], scaled)
#define OFF_SB  4456448         // 2048*8 floats (score bias, scaled)
#define OFF_CTX 4472832         // 2048*2048 floats (ctx, [i][k*8+h])

// async global->LDS, 16B per lane; lds dst is wave-uniform base (HW adds lane*16)
#define GLOAD_LDS16(g, l)                                                      \
    __builtin_amdgcn_global_load_lds(                                          \
        (const __attribute__((address_space(1))) unsigned int*)(g),            \
        (__attribute__((address_space(3))) unsigned int*)(l), 16, 0, 0)

// ---------------- K0: transpose Wq,Wk,Wv,out_w into ws ----------------
__global__ __launch_bounds__(256) void k0_transpose(const float* __restrict__ ipw,
                                                    const float* __restrict__ ow,
                                                    float* __restrict__ ws) {
    __shared__ float tile[32][33];
    int bx = blockIdx.x;
    int mat = bx >> 6, tl = bx & 63;
    int tr0 = (tl >> 3) << 5, tc0 = (tl & 7) << 5;
    const float* src;
    float* dst;
    if (mat == 3) { src = ow;             dst = ws + OFF_OWT; }
    else          { src = ipw + mat*65536; dst = ws + OFF_WQT + mat*65536; }
    int c = threadIdx.x & 31, r0 = threadIdx.x >> 5;
    #pragma unroll
    for (int k = 0; k < 4; k++) {
        int r = r0 + k*8;
        tile[r][c] = src[(tr0 + r)*256 + tc0 + c];
    }
    __syncthreads();
    #pragma unroll
    for (int k = 0; k < 4; k++) {
        int r = r0 + k*8;
        dst[(tc0 + r)*256 + tr0 + c] = tile[c][r];
    }
}

// ---------------- K1: qh -> rq (Wk folded into q) + score bias ----------------
// dyn LDS = 67584 B: rqt[8][16*132] (plane layout [ii][h2p*132 + s])
__global__ __launch_bounds__(512) void k1_qrq(const float* __restrict__ x,
                                              const float* __restrict__ ipw,
                                              const float* __restrict__ ipb,
                                              float* __restrict__ ws) {
    __shared__ float x8[2048];     // 8 tokens x 256
    __shared__ float qpart[4096];  // 2 halves x 8 x 256
    __shared__ float qh[2048];     // 8 x 256
    extern __shared__ float rqt[]; // 8 x 2112 floats
    const float* wqT = ws + OFF_WQT;
    const float* wk  = ipw + 65536;   // Wk raw: wk[r*256 + c] = Wk[r][c]
    float* rqw = ws + OFF_RQ;
    float* sbw = ws + OFF_SB;
    int tid = threadIdx.x;
    long i0 = (long)blockIdx.x * 8;

    ((float4*)x8)[tid] = ((const float4*)(x + i0*256))[tid];
    __syncthreads();

    int c = tid & 255, half = tid >> 8;
    {   // qh partials over cc-half
        float qa[8];
        #pragma unroll
        for (int ii = 0; ii < 8; ii++) qa[ii] = 0.f;
        int cc0 = half*128;
        #pragma unroll 8
        for (int cc = cc0; cc < cc0 + 128; cc++) {
            float w = wqT[cc*256 + c];
            #pragma unroll
            for (int ii = 0; ii < 8; ii++) qa[ii] += x8[ii*256 + cc]*w;
        }
        #pragma unroll
        for (int ii = 0; ii < 8; ii++) qpart[(half*8 + ii)*256 + c] = qa[ii];
    }
    __syncthreads();
    if (tid < 256) {
        float b = ipb[tid];
        #pragma unroll
        for (int ii = 0; ii < 8; ii++)
            qh[ii*256 + tid] = qpart[ii*256 + tid] + qpart[(8 + ii)*256 + tid] + b;
    }
    __syncthreads();
    {   // rq compute -> LDS tile.  rq[h,k] = SCL * sum_hd qh[h*32+hd] * Wk[h*32+hd, k]
        int k = tid & 255, hh = tid >> 8;
        int s = k & 127, par = k >> 7;
        for (int h = hh*4; h < hh*4 + 4; h++) {
            float ra[8];
            #pragma unroll
            for (int ii = 0; ii < 8; ii++) ra[ii] = 0.f;
            #pragma unroll 8
            for (int hd = 0; hd < 32; hd++) {
                float w = wk[(h*32 + hd)*256 + k];   // coalesced over k
                #pragma unroll
                for (int ii = 0; ii < 8; ii++) ra[ii] += qh[ii*256 + h*32 + hd]*w;
            }
            int h2p = h*2 + par;
            #pragma unroll
            for (int ii = 0; ii < 8; ii++)
                rqt[ii*2112 + h2p*132 + s] = ra[ii]*SCL;
        }
    }
    __syncthreads();
    {   // flush: global layout [i][s*16 + h2p], fully coalesced float4 stores
        float4* dst = (float4*)(rqw + i0*2048);
        #pragma unroll
        for (int it = 0; it < 8; it++) {
            int f = it*512 + tid;          // ii = it (512 float4 per token)
            int s = (f & 511) >> 2, q = f & 3;
            int base = it*2112 + s;
            float4 v;
            v.x = rqt[base + (4*q + 0)*132];
            v.y = rqt[base + (4*q + 1)*132];
            v.z = rqt[base + (4*q + 2)*132];
            v.w = rqt[base + (4*q + 3)*132];
            dst[f] = v;
        }
    }
    if (tid < 64) {  // score bias = (qh . bk_h)/sqrt(32)
        int ii = tid >> 3, h = tid & 7;
        float s = 0.f;
        #pragma unroll 8
        for (int hd = 0; hd < 32; hd++) s += qh[ii*256 + h*32 + hd]*ipb[256 + h*32 + hd];
        sbw[(i0 + ii)*8 + h] = s*SCL;
    }
}

// ---------------- K2: main attention (one block per token) ----------------
// R11: 1024 threads / 16 waves (was 512/8) — latency hiding; same LDS 157696 B.
// Scores: wave (q=w>>2, hh4=w&3) owns 2 heads: per s = 1 uniform b128 rq + 1 b128 xv.
__global__ __launch_bounds__(1024) void k2_attn(const float* __restrict__ x,
                                                float* __restrict__ ws) {
    extern __shared__ float sm[];
    float* xw   = sm;                  // 33280 floats, row stride 260
    float* rq2  = sm + 33280;          // 2048 floats, [s*16 + h*2 + par]
    float* scp  = sm + 33280 + 2048;   // 4096 floats, [q*1024 + h*128 + j]
    float* attn = rq2;                 // alias (rq2 dead after scores)
    const float* rqw = ws + OFF_RQ;
    const float* sbw = ws + OFF_SB;
    float* ctxw = ws + OFF_CTX;
    int tid = threadIdx.x;
    int i = blockIdx.x;
    int t = i & (TT - 1);
    int w = tid >> 6, lane = tid & 63;

    // ---- stage window (8 rows/wave) + rq (waves 0-7) ----
    {
        #pragma unroll
        for (int it = 0; it < 8; it++) {
            int r = it*16 + w;                // wave-uniform row 0..127
            int ts = t - 127 + r;
            float* lrow = xw + r*260;
            if (ts >= 0) {
                const float* g = x + (long)(i - 127 + r)*256 + lane*4;
                GLOAD_LDS16(g, lrow);
            } else {
                float4 z = {0.f, 0.f, 0.f, 0.f};
                *(float4*)(lrow + lane*4) = z;
            }
        }
        if (w < 8) {
            const float* g = rqw + (long)i*2048 + w*256 + lane*4;
            GLOAD_LDS16(g, rq2 + w*256);
        }
    }
    __syncthreads();

    // ---- scores: wave (q, hh4) -> heads 2hh4,2hh4+1; lane jj2 = j-pair ----
    {
        int jj2 = lane;
        int q = w >> 2, hh4 = w & 3;
        float a00=0.f,a01=0.f,a10=0.f,a11=0.f;
        const float4* rq4 = (const float4*)rq2;
        int s0 = q*32;
        #pragma unroll 4
        for (int s = s0; s < s0 + 32; s++) {
            float4 xv = *(const float4*)&xw[s*260 + 4*jj2];  // (j0p0)(j0p1)(j1p0)(j1p1)
            float4 r0 = rq4[s*4 + hh4];                      // (h0p0)(h0p1)(h1p0)(h1p1)
            a00 += r0.x*xv.x + r0.y*xv.y;  a01 += r0.x*xv.z + r0.y*xv.w;
            a10 += r0.z*xv.x + r0.w*xv.y;  a11 += r0.z*xv.z + r0.w*xv.w;
        }
        float2* sc2 = (float2*)scp;            // idx = q*512 + h*64 + jj2
        float2 v0 = {a00, a01}; sc2[q*512 + (2*hh4+0)*64 + jj2] = v0;
        float2 v1 = {a10, a11}; sc2[q*512 + (2*hh4+1)*64 + jj2] = v1;
    }
    __syncthreads();

    // ---- softmax: waves 0-7 (h=w), lane l covers j=l and j=l+64 ----
    if (w < 8) {
        int h = w, l = lane;
        float sb = sbw[i*8 + h];
        float s1 = sb, s2 = sb;
        #pragma unroll
        for (int q = 0; q < 4; q++) {
            s1 += scp[q*1024 + h*128 + l];
            s2 += scp[q*1024 + h*128 + l + 64];
        }
        int lim = 127 - t;
        bool m1 = l < lim, m2 = (l + 64) < lim;
        if (m1) s1 = -1e30f;
        if (m2) s2 = -1e30f;
        float m = fmaxf(s1, s2);
        #pragma unroll
        for (int d = 1; d < 64; d <<= 1) m = fmaxf(m, __shfl_xor(m, d, 64));
        float e1 = m1 ? 0.f : __expf(s1 - m);
        float e2 = m2 ? 0.f : __expf(s2 - m);
        float sum = e1 + e2;
        #pragma unroll
        for (int d = 1; d < 64; d <<= 1) sum += __shfl_xor(sum, d, 64);
        float r = 1.0f / sum;
        attn[l*8 + h] = e1*r;
        attn[(l + 64)*8 + h] = e2*r;
    }
    __syncthreads();

    // ---- ctx: thread (sC, jq 0..7) accumulates [p][h] (16 accs) over 16 j ----
    {
        int sC = tid & 127, jq = tid >> 7;
        float cac[16];
        #pragma unroll
        for (int c = 0; c < 16; c++) cac[c] = 0.f;
        #pragma unroll 4
        for (int j = jq*16; j < jq*16 + 16; j++) {
            float2 x2 = *(const float2*)&xw[sC*260 + 2*j];
            float4 a0 = *(const float4*)&attn[j*8];
            float4 a1 = *(const float4*)&attn[j*8 + 4];
            cac[0]  += a0.x*x2.x; cac[1]  += a0.y*x2.x; cac[2]  += a0.z*x2.x; cac[3]  += a0.w*x2.x;
            cac[4]  += a1.x*x2.x; cac[5]  += a1.y*x2.x; cac[6]  += a1.z*x2.x; cac[7]  += a1.w*x2.x;
            cac[8]  += a0.x*x2.y; cac[9]  += a0.y*x2.y; cac[10] += a0.z*x2.y; cac[11] += a0.w*x2.y;
            cac[12] += a1.x*x2.y; cac[13] += a1.y*x2.y; cac[14] += a1.z*x2.y; cac[15] += a1.w*x2.y;
        }
        __syncthreads();  // all xw reads done -> safe to overwrite xw with partials
        #pragma unroll
        for (int c = 0; c < 16; c++) xw[c*1024 + tid] = cac[c];  // [c][thr], conflict-free
    }
    __syncthreads();

    // ---- reduce 8 j-quarters, write ctx[i][k*8+h] ----
    if (tid < 256) {
        int k = tid, p = k >> 7;
        float v[8];
        #pragma unroll
        for (int h = 0; h < 8; h++) v[h] = 0.f;
        #pragma unroll
        for (int jq = 0; jq < 8; jq++) {
            int thr = jq*128 + (k & 127);
            #pragma unroll
            for (int h = 0; h < 8; h++) v[h] += xw[(p*8 + h)*1024 + thr];
        }
        float4* dst = (float4*)(ctxw + (long)i*2048 + k*8);
        float4 o0 = {v[0], v[1], v[2], v[3]};
        float4 o1 = {v[4], v[5], v[6], v[7]};
        dst[0] = o0; dst[1] = o1;
    }
}

// ---------------- K3: out = out_w @ (Wv_blockdiag @ ctx + bv) + out_b ----------------
// R11: 4 tokens/block, grid 512, LDS 45056 B -> 2 blocks/CU (16 waves/CU).
// ctx8T[kh8*4 + ii]: staged via 4 coalesced b32 reads + 1 b128 LDS write per kh8.
__global__ __launch_bounds__(512) void k3_proj(const float* __restrict__ ipb,
                                               const float* __restrict__ ob,
                                               float* __restrict__ ws,
                                               float* __restrict__ out) {
    extern __shared__ float sm[];
    float* ctx8T  = sm;                    // 8192 floats: [kh8][ii 0..3]
    float* oppart = sm + 8192;             // 2 x 4 x 256
    float* op     = sm + 8192 + 2048;      // 4 x 256
    const float* wvT  = ws + OFF_WVT;
    const float* owT  = ws + OFF_OWT;
    const float* ctxw = ws + OFF_CTX;
    int tid = threadIdx.x;
    long i0 = (long)blockIdx.x * 4;

    {   // stage transposed: global [ii][kh8] -> LDS [kh8][ii]
        const float* src = ctxw + i0*2048;
        #pragma unroll
        for (int it = 0; it < 4; it++) {
            int kh8 = it*512 + tid;
            float4 v;
            #pragma unroll
            for (int ii = 0; ii < 4; ii++)
                (&v.x)[ii] = src[ii*2048 + kh8];   // coalesced over tid
            *(float4*)&ctx8T[kh8*4] = v;           // b128, structural-min banks
        }
    }
    __syncthreads();

    int c = tid & 255, kh = tid >> 8;
    {   // out_pre partials: per-head Wv fold (1 b128 ctx read per k)
        int h = c >> 5;
        float acc[4];
        #pragma unroll
        for (int ii = 0; ii < 4; ii++) acc[ii] = 0.f;
        #pragma unroll 8
        for (int k = kh*128; k < kh*128 + 128; k++) {
            float w = wvT[k*256 + c];
            float4 cv = *(const float4*)&ctx8T[(k*8 + h)*4];
            acc[0] += w*cv.x; acc[1] += w*cv.y; acc[2] += w*cv.z; acc[3] += w*cv.w;
        }
        #pragma unroll
        for (int ii = 0; ii < 4; ii++) oppart[(kh*4 + ii)*256 + c] = acc[ii];
    }
    __syncthreads();
    if (tid < 256) {
        float b = ipb[512 + tid];
        #pragma unroll
        for (int ii = 0; ii < 4; ii++)
            op[ii*256 + tid] = oppart[ii*256 + tid] + oppart[(4 + ii)*256 + tid] + b;
    }
    __syncthreads();
    {   // final projection partials
        float acc[4];
        #pragma unroll
        for (int ii = 0; ii < 4; ii++) acc[ii] = 0.f;
        #pragma unroll 8
        for (int cc = kh*128; cc < kh*128 + 128; cc++) {
            float w = owT[cc*256 + c];
            #pragma unroll
            for (int ii = 0; ii < 4; ii++) acc[ii] += w*op[ii*256 + cc];
        }
        #pragma unroll
        for (int ii = 0; ii < 4; ii++) oppart[(kh*4 + ii)*256 + c] = acc[ii];
    }
    __syncthreads();
    if (tid < 256) {
        float b = ob[tid];
        #pragma unroll
        for (int ii = 0; ii < 4; ii++)
            out[(i0 + ii)*256 + tid] = oppart[ii*256 + tid] + oppart[(4 + ii)*256 + tid] + b;
    }
}

extern "C" void kernel_launch(void* const* d_in, const int* in_sizes, int n_in,
                              void* d_out, int out_size, void* d_ws, size_t ws_size,
                              hipStream_t stream) {
    const float* x   = (const float*)d_in[0];   // (2,1024,256)
    const float* ipw = (const float*)d_in[1];   // (768,256)
    const float* ipb = (const float*)d_in[2];   // (768)
    const float* ow  = (const float*)d_in[3];   // (256,256)
    const float* ob  = (const float*)d_in[4];   // (256)
    float* out = (float*)d_out;
    float* ws  = (float*)d_ws;                  // needs ~33.1 MB

    (void)in_sizes; (void)n_in; (void)out_size; (void)ws_size;

    // allow >64KB dynamic LDS (idempotent; host-side, graph-capture safe)
    hipFuncSetAttribute(reinterpret_cast<const void*>(k1_qrq),
                        hipFuncAttributeMaxDynamicSharedMemorySize, 67584);
    hipFuncSetAttribute(reinterpret_cast<const void*>(k2_attn),
                        hipFuncAttributeMaxDynamicSharedMemorySize, 157696);
    hipFuncSetAttribute(reinterpret_cast<const void*>(k3_proj),
                        hipFuncAttributeMaxDynamicSharedMemorySize, 45056);

    hipLaunchKernelGGL(k0_transpose, dim3(256),  dim3(256),  0,      stream, ipw, ow, ws);
    hipLaunchKernelGGL(k1_qrq,       dim3(256),  dim3(512),  67584,  stream, x, ipw, ipb, ws);
    hipLaunchKernelGGL(k2_attn,      dim3(2048), dim3(1024), 157696, stream, x, ws);
    hipLaunchKernelGGL(k3_proj,      dim3(512),  dim3(512),  45056,  stream, ipb, ob, ws, out);
}